// Round 7
// baseline (375.405 us; speedup 1.0000x reference)
//
#include <hip/hip_runtime.h>

#define B_    8
#define CIN_  256
#define H_    128
#define W_    128
#define CC_   16
#define COUT_ 64
#define HFP_  132            // fpad padded dim (pad 2)
#define HW_   (H_ * W_)
#define XHP_  130            // xh padded dim (pad 1)
#define XH_IMG   ((size_t)32 * XHP_ * XHP_ * 8)   // 4,326,400 f16 per image
#define XH_CHUNK (4 * XHP_ * XHP_ * 8)            // 540,800 f16 per 32-cin chunk

// old-path LDS staging constants (fallback kernel)
#define XS_STRIDE 1634
#define XS_BUF    (4 * XS_STRIDE)

typedef _Float16 half8 __attribute__((ext_vector_type(8)));
typedef float float4v __attribute__((ext_vector_type(4)));

__device__ __forceinline__ void gload16(const _Float16* g, _Float16* l) {
    __builtin_amdgcn_global_load_lds(
        (const __attribute__((address_space(1))) void*)g,
        (__attribute__((address_space(3))) void*)l, 16, 0, 0);
}

// ---------------------------------------------------------------------------
// PREP (one dispatch): x->xh f16 transpose+pad, xh border zero,
// fpad border zero, repack Wext->Wa1, repack Wreg->Wa2. Roles by blockIdx.
// ---------------------------------------------------------------------------
__global__ __launch_bounds__(256) void prep(
    const float* __restrict__ x, const float* __restrict__ Wext,
    const float* __restrict__ Wreg, _Float16* __restrict__ xh,
    _Float16* __restrict__ Wa1, _Float16* __restrict__ Wa2,
    _Float16* __restrict__ fpad)
{
    const int bid = blockIdx.x;
    const int t   = threadIdx.x;
    if (bid < 16384) {
        // xh interior: task = (img, c8, h); 2 tasks/block, 128 px each
        const int task = bid * 2 + (t >> 7);
        const int img  = task >> 12;
        const int rem  = task & 4095;
        const int c8   = rem >> 7;
        const int h    = rem & 127;
        const int w    = t & 127;
        const float* xp = x + ((size_t)(img * 256 + c8 * 8)) * HW_ + h * W_ + w;
        half8 hv;
#pragma unroll
        for (int j = 0; j < 8; ++j) hv[j] = (_Float16)xp[j * HW_];
        *(half8*)(xh + ((((size_t)img * 32 + c8) * XHP_ + (h + 1)) * XHP_ + (w + 1)) * 8) = hv;
    } else if (bid < 16900) {
        // xh border zero: 516 px per (img,c8), 16B each; 516*256 = 132096 exact
        const int e  = (bid - 16384) * 256 + t;
        const int ic = e / 516;
        const int pe = e % 516;
        const int img = ic >> 5, c8 = ic & 31;
        int hp, wp;
        if (pe < 130)      { hp = 0;              wp = pe; }
        else if (pe < 260) { hp = 129;            wp = pe - 130; }
        else if (pe < 388) { hp = 1 + (pe - 260); wp = 0; }
        else               { hp = 1 + (pe - 388); wp = 129; }
        half8 z = {};
        *(half8*)(xh + ((((size_t)img * 32 + c8) * XHP_ + hp) * XHP_ + wp) * 8) = z;
    } else if (bid < 16965) {
        // fpad border zero: 1040 px/img * 2 halves * 8 img = 16640 units of 16B
        const int e = (bid - 16900) * 256 + t;
        if (e < 16640) {
            const int img = e / 2080;
            const int r   = e % 2080;
            const int pxi = r >> 1, hf = r & 1;
            int hp, wp;
            if (pxi < 264)      { hp = pxi / 132;                wp = pxi % 132; }
            else if (pxi < 528) { int pz = pxi - 264; hp = 130 + pz / 132; wp = pz % 132; }
            else { int q2 = pxi - 528; hp = 2 + (q2 >> 2); int s2 = q2 & 3;
                   wp = (s2 < 2) ? s2 : 128 + (s2 - 2); }
            half8 z = {};
            *(half8*)(fpad + (((size_t)img * HFP_ + hp) * HFP_ + wp) * 16 + hf * 8) = z;
        }
    } else if (bid < 17109) {
        // repack_w1: 144*256 = 36864 exact
        const int i = (bid - 16965) * 256 + t;
        const int j = i & 7, lane = (i >> 3) & 63, blk = (i >> 9) & 7, tap = i >> 12;
        const int cc  = lane & 15;
        const int cin = blk * 32 + (lane >> 4) * 8 + j;
        Wa1[i] = (_Float16)Wext[cc * (CIN_ * 9) + cin * 9 + tap];
    } else {
        // repack_w2: 104*256 = 26624 exact
        const int u = (bid - 17109) * 256 + t;
        const int j = u & 7, lane = (u >> 3) & 63;
        const int su = u >> 9, s = su % 13, g = su / 13;
        const int q = lane >> 4;
        int kk = 2 * s + (q >> 1);
        const int c = (q & 1) * 8 + j;
        const int o = g * 16 + (lane & 15);
        float v = (kk < 25) ? Wreg[o * (CC_ * 25) + c * 25 + kk] : 0.0f;
        Wa2[u] = (_Float16)v;
    }
}

// ---------------------------------------------------------------------------
// Fused Stage 1 v2: staging via global_load_lds from padded f16 xh.
// (round-5/6 bytes, verbatim)
// ---------------------------------------------------------------------------
__global__ __launch_bounds__(256, 4) void conv_fused2(
    const _Float16* __restrict__ xh, const _Float16* __restrict__ Wa1,
    const float* __restrict__ bext, _Float16* __restrict__ fpad)
{
    __shared__ _Float16 xs[2 * 6528];        // 26,112 B double-buffered staging
    __shared__ _Float16 lt[4][32][16];       // 4,096 B epilogue transpose

    const int lane = threadIdx.x;
    const int wv   = threadIdx.y;
    const int n    = lane & 15;
    const int q    = lane >> 4;

    // XCD swizzle: f bijective over 0..1023; b = f&7 pins image -> XCD
    const int f  = blockIdx.x + 4 * blockIdx.y + 128 * blockIdx.z;
    const int b  = f & 7;
    const int wt = (f >> 3) & 3;
    const int ht = f >> 5;
    const int h0 = ht * 4;
    const int w0 = wt * 32;

    // staging descriptors: unit u = wv*204 + k*64 + lane over [c8][row][col]
    const _Float16* xhb = xh + (size_t)b * XH_IMG;
    const _Float16* g[4];
#pragma unroll
    for (int k = 0; k < 4; ++k) {
        int u = wv * 204 + k * 64 + lane;
        if (k == 3 && lane >= 12) u = wv * 204;     // inactive lane, safe addr
        const int c8  = u / 204;
        const int rem = u % 204;
        const int row = rem / 34;
        const int col = rem % 34;
        g[k] = xhb + (((size_t)c8 * XHP_ + (h0 + row)) * XHP_ + (w0 + col)) * 8;
    }

    // prologue: stage chunk 0 -> buf0
#pragma unroll
    for (int k = 0; k < 4; ++k) {
        if (k < 3 || lane < 12) gload16(g[k], xs + (wv * 204 + k * 64) * 8);
        g[k] += XH_CHUNK;
    }
    asm volatile("s_waitcnt vmcnt(0)" ::: "memory");

    float4v acc[2] = {};
    for (int chunk = 0; chunk < 8; ++chunk) {
        __syncthreads();                     // xs[cur] staged by all waves
        const int cur = chunk & 1;

        if (chunk < 7) {
            _Float16* xd = xs + (cur ^ 1) * 6528;
#pragma unroll
            for (int k = 0; k < 4; ++k) {
                if (k < 3 || lane < 12) gload16(g[k], xd + (wv * 204 + k * 64) * 8);
                g[k] += XH_CHUNK;
            }
        }

        const _Float16* wchunk = Wa1 + (size_t)chunk * 512 + lane * 8;
        const _Float16* xsb    = xs + cur * 6528 + ((q * 6 + wv) * 34 + n) * 8;
#pragma unroll
        for (int r = 0; r < 3; ++r) {
#pragma unroll
            for (int s = 0; s < 3; ++s) {
                const half8 af = *(const half8*)(wchunk + (r * 3 + s) * 4096);
#pragma unroll
                for (int st = 0; st < 2; ++st) {
                    const half8 bf = *(const half8*)(xsb + (r * 34 + s + st * 16) * 8);
                    acc[st] = __builtin_amdgcn_mfma_f32_16x16x32_f16(af, bf, acc[st], 0, 0, 0);
                }
            }
        }
        asm volatile("s_waitcnt vmcnt(0)" ::: "memory");  // my DMA landed before barrier
    }

    // ---- epilogue: bias + f32->f16, per-wave LDS transpose, write fpad ----
    float bias[4];
#pragma unroll
    for (int rr = 0; rr < 4; ++rr) bias[rr] = bext[q * 4 + rr];

#pragma unroll
    for (int st = 0; st < 2; ++st) {
#pragma unroll
        for (int rr = 0; rr < 4; ++rr) {
            lt[wv][st * 16 + n][q * 4 + rr] = (_Float16)(acc[st][rr] + bias[rr]);
        }
    }
    __syncthreads();

    const half8 o = *(const half8*)&lt[wv][lane >> 1][(lane & 1) * 8];
    _Float16* dst = fpad + (((size_t)b * HFP_ + (h0 + wv + 2)) * HFP_ + (w0 + (lane >> 1) + 2)) * 16
                    + (lane & 1) * 8;
    *(half8*)dst = o;
}

// ---------------------------------------------------------------------------
// FALLBACK kernels (used when ws_size is too small for xh).
// ---------------------------------------------------------------------------
__global__ void repack_w1(const float* __restrict__ Wext, _Float16* __restrict__ Wa1) {
    int i = blockIdx.x * 256 + threadIdx.x;
    if (i >= 9 * 8 * 64 * 8) return;
    int j    = i & 7;
    int lane = (i >> 3) & 63;
    int blk  = (i >> 9) & 7;
    int tap  = i >> 12;
    int cc   = lane & 15;
    int cin  = blk * 32 + (lane >> 4) * 8 + j;
    Wa1[i] = (_Float16)Wext[cc * (CIN_ * 9) + cin * 9 + tap];
}

__global__ void repack_w2(const float* __restrict__ Wreg, _Float16* __restrict__ Wa2) {
    int u = blockIdx.x * 256 + threadIdx.x;
    if (u >= 4 * 13 * 64 * 8) return;
    int j    = u & 7;
    int lane = (u >> 3) & 63;
    int su   = u >> 9;
    int s    = su % 13;
    int g    = su / 13;
    int q    = lane >> 4;
    int kk   = 2 * s + (q >> 1);
    int c    = (q & 1) * 8 + j;
    int o    = g * 16 + (lane & 15);
    float v  = (kk < 25) ? Wreg[o * (CC_ * 25) + c * 25 + kk] : 0.0f;
    Wa2[u] = (_Float16)v;
}

__global__ __launch_bounds__(256, 4) void conv_fused(
    const float* __restrict__ x, const _Float16* __restrict__ Wa1,
    const float* __restrict__ bext, _Float16* __restrict__ fpad)
{
    __shared__ _Float16 xs[2 * XS_BUF];
    __shared__ _Float16 lt[4][32][16];

    const int lane = threadIdx.x;
    const int wv   = threadIdx.y;
    const int tid  = wv * 64 + lane;
    const int n    = lane & 15;
    const int q    = lane >> 4;

    const int f  = blockIdx.x + 4 * blockIdx.y + 128 * blockIdx.z;
    const int b  = f & 7;
    const int wt = (f >> 3) & 3;
    const int ht = f >> 5;
    const int h0 = ht * 4;
    const int w0 = wt * 32;

    int  goff[4];
    int  loff[4];
    bool vld[4];
    bool act[4];
#pragma unroll
    for (int p = 0; p < 4; ++p) {
        int u = p * 256 + tid;
        act[p] = (u < 816);
        if (!act[p]) u = 0;
        const int col  = u % 34;
        const int pair = u / 34;
        const int row  = pair % 6;
        const int c8   = pair / 6;
        const int hh = h0 - 1 + row;
        const int ww = w0 - 1 + col;
        vld[p] = (hh >= 0) && (hh < H_) && (ww >= 0) && (ww < W_);
        const int hc = hh < 0 ? 0 : (hh > H_ - 1 ? H_ - 1 : hh);
        const int wc = ww < 0 ? 0 : (ww > W_ - 1 ? W_ - 1 : ww);
        goff[p] = (c8 * 8) * HW_ + hc * W_ + wc;
        loff[p] = c8 * XS_STRIDE + (row * 34 + col) * 8;
    }

    const float* xb = x + (size_t)b * (CIN_ * HW_);
    float4v acc[2] = {};

#pragma unroll
    for (int p = 0; p < 4; ++p) {
        if (act[p]) {
            half8 hv;
#pragma unroll
            for (int j = 0; j < 8; ++j) {
                const float v = xb[goff[p] + j * HW_];
                hv[j] = (_Float16)(vld[p] ? v : 0.0f);
            }
            *(half8*)(xs + loff[p]) = hv;
        }
    }

    float pf[4][8];
    for (int chunk = 0; chunk < 8; ++chunk) {
        __syncthreads();
        const int cur = chunk & 1;

        if (chunk < 7) {
            const float* xc = xb + (size_t)(chunk + 1) * (32 * HW_);
#pragma unroll
            for (int p = 0; p < 4; ++p) {
                if (act[p]) {
#pragma unroll
                    for (int j = 0; j < 8; ++j)
                        pf[p][j] = xc[goff[p] + j * HW_];
                }
            }
        }

        const _Float16* wchunk = Wa1 + (size_t)chunk * 512 + lane * 8;
        const _Float16* xsb    = xs + cur * XS_BUF + q * XS_STRIDE + (wv * 34 + n) * 8;
#pragma unroll
        for (int r = 0; r < 3; ++r) {
#pragma unroll
            for (int s = 0; s < 3; ++s) {
                const half8 af = *(const half8*)(wchunk + (r * 3 + s) * 4096);
#pragma unroll
                for (int st = 0; st < 2; ++st) {
                    const half8 bf = *(const half8*)(xsb + (r * 34 + s + st * 16) * 8);
                    acc[st] = __builtin_amdgcn_mfma_f32_16x16x32_f16(af, bf, acc[st], 0, 0, 0);
                }
            }
        }

        if (chunk < 7) {
            _Float16* xd = xs + (cur ^ 1) * XS_BUF;
#pragma unroll
            for (int p = 0; p < 4; ++p) {
                if (act[p]) {
                    half8 hv;
#pragma unroll
                    for (int j = 0; j < 8; ++j)
                        hv[j] = (_Float16)(vld[p] ? pf[p][j] : 0.0f);
                    *(half8*)(xd + loff[p]) = hv;
                }
            }
        }
    }

    float bias[4];
#pragma unroll
    for (int rr = 0; rr < 4; ++rr) bias[rr] = bext[q * 4 + rr];

#pragma unroll
    for (int st = 0; st < 2; ++st) {
#pragma unroll
        for (int rr = 0; rr < 4; ++rr) {
            lt[wv][st * 16 + n][q * 4 + rr] = (_Float16)(acc[st][rr] + bias[rr]);
        }
    }
    __syncthreads();

    const half8 o = *(const half8*)&lt[wv][lane >> 1][(lane & 1) * 8];
    _Float16* dst = fpad + (((size_t)b * HFP_ + (h0 + wv + 2)) * HFP_ + (w0 + (lane >> 1) + 2)) * 16
                    + (lane & 1) * 8;
    *(half8*)dst = o;
}

// ---------------------------------------------------------------------------
// Stage 2: corr + regressor via MFMA.
// DIAGNOSTIC ROUND: body wrapped in REP=2 loop with a memory fence so the
// second pass truly re-executes (idempotent — identical values written to
// the same addresses). Doubles corr's duration (~150-170us) so it MUST rank
// above the ~80us workspace fills in the top-5 and expose its true counters
// (VGPR/Occupancy/MfmaUtil/VALUBusy/FETCH). Reverts to REP=1 next round.
// ---------------------------------------------------------------------------
#define CORR_REP 2

__global__ __launch_bounds__(256, 4) void corr_mfma(
    const _Float16* __restrict__ fpad, const _Float16* __restrict__ Wa2,
    float* __restrict__ out)
{
    const int lane = threadIdx.x;
    const int wv   = threadIdx.y;
    const int n    = lane & 15;
    const int q    = lane >> 4;

    const int f  = blockIdx.x + 2 * blockIdx.y + 256 * blockIdx.z;
    const int b  = f & 7;
    const int xt = (f >> 3) & 1;
    const int h  = f >> 4;
    const int w0 = xt * 64 + wv * 16;

    const _Float16* fb = fpad + ((size_t)b * HFP_ + h) * (HFP_ * 16);
    const int coff = (q & 1) * 8;

#pragma unroll 1
    for (int rep = 0; rep < CORR_REP; ++rep) {
        asm volatile("" ::: "memory");        // defeat cross-rep CSE: loads re-issue

        // issue all 14 loads (ctr + 13 shifted fragments) as one batch
        const half8 ctr = *(const half8*)(fb + (size_t)(2 * HFP_ + (w0 + n + 2)) * 16 + coff);
        half8 sh[13];
#pragma unroll
        for (int s = 0; s < 13; ++s) {
            int kk = 2 * s + (q >> 1);
            if (kk > 24) kk = 24;             // s=12,q>=2: weights are zero
            const int ki = kk / 5, kj = kk % 5;
            sh[s] = *(const half8*)(fb + (size_t)(ki * HFP_ + (w0 + n + kj)) * 16 + coff);
        }
        __builtin_amdgcn_sched_barrier(0);    // loads may not sink below here

        float4v acc[4] = {};
        const _Float16* wp = Wa2 + (size_t)lane * 8;
#pragma unroll
        for (int s = 0; s < 13; ++s) {
            const half8 c = ctr * sh[s];      // single temp, consumed immediately
#pragma unroll
            for (int g = 0; g < 4; ++g) {
                const half8 wf = *(const half8*)(wp + (size_t)(g * 13 + s) * 512);
                acc[g] = __builtin_amdgcn_mfma_f32_16x16x32_f16(wf, c, acc[g], 0, 0, 0);
            }
        }

#pragma unroll
        for (int g = 0; g < 4; ++g) {
#pragma unroll
            for (int rr = 0; rr < 4; ++rr) {
                const int o = g * 16 + q * 4 + rr;
                out[((size_t)(b * COUT_ + o) * H_ + h) * W_ + (w0 + n)] = acc[g][rr];
            }
        }
    }
}

// ---------------------------------------------------------------------------
extern "C" void kernel_launch(void* const* d_in, const int* in_sizes, int n_in,
                              void* d_out, int out_size, void* d_ws, size_t ws_size,
                              hipStream_t stream) {
    const float* x    = (const float*)d_in[0];  // (8,256,128,128)
    const float* Wext = (const float*)d_in[1];  // (16,256,3,3)
    const float* bext = (const float*)d_in[2];  // (16,)
    const float* Wreg = (const float*)d_in[3];  // (64,16,5,5)
    float* out = (float*)d_out;                 // (8,64,128,128)

    char* ws = (char*)d_ws;
    _Float16* fpad = (_Float16*)ws;                       // 4,460,544 B
    _Float16* Wa1  = (_Float16*)(ws + 4460544);           // 73,728 B
    _Float16* Wa2  = (_Float16*)(ws + 4460544 + 73728);   // 53,248 B
    const size_t XH_OFF = 4460544 + 73728 + 53248;        // 4,587,520
    const size_t XH_B   = (size_t)8 * 32 * XHP_ * XHP_ * 8 * 2;  // 69,222,400

    if (ws_size >= XH_OFF + XH_B) {
        _Float16* xh = (_Float16*)(ws + XH_OFF);
        prep<<<dim3(17213), dim3(256), 0, stream>>>(x, Wext, Wreg, xh, Wa1, Wa2, fpad);
        conv_fused2<<<dim3(4, 32, 8), dim3(64, 4), 0, stream>>>(xh, Wa1, bext, fpad);
        corr_mfma<<<dim3(2, 128, 8), dim3(64, 4), 0, stream>>>(fpad, Wa2, out);
    } else {
        repack_w1<<<dim3(144), dim3(256), 0, stream>>>(Wext, Wa1);
        repack_w2<<<dim3(104), dim3(256), 0, stream>>>(Wreg, Wa2);
        hipMemsetAsync(fpad, 0, (size_t)B_ * CC_ * HFP_ * HFP_ * sizeof(_Float16), stream);
        conv_fused<<<dim3(4, 32, 8), dim3(64, 4), 0, stream>>>(x, Wa1, bext, fpad);
        corr_mfma<<<dim3(2, 128, 8), dim3(64, 4), 0, stream>>>(fpad, Wa2, out);
    }
}

// Round 8
// 247.373 us; speedup vs baseline: 1.5176x; 1.5176x over previous
//
#include <hip/hip_runtime.h>

#define B_    8
#define CIN_  256
#define H_    128
#define W_    128
#define CC_   16
#define COUT_ 64
#define HFP_  132            // fpad padded dim (pad 2)
#define HW_   (H_ * W_)
#define XHP_  130            // xh padded dim (pad 1)
#define XH_IMG   ((size_t)32 * XHP_ * XHP_ * 8)   // 4,326,400 f16 per image
#define XH_CHUNK (4 * XHP_ * XHP_ * 8)            // 540,800 f16 per 32-cin chunk

// old-path LDS staging constants (fallback kernel)
#define XS_STRIDE 1634
#define XS_BUF    (4 * XS_STRIDE)

typedef _Float16 half8 __attribute__((ext_vector_type(8)));
typedef float float4v __attribute__((ext_vector_type(4)));

__device__ __forceinline__ void gload16(const _Float16* g, _Float16* l) {
    __builtin_amdgcn_global_load_lds(
        (const __attribute__((address_space(1))) void*)g,
        (__attribute__((address_space(3))) void*)l, 16, 0, 0);
}

// ---------------------------------------------------------------------------
// PREP (one dispatch): x->xh f16 transpose+pad, xh border zero,
// fpad border zero, repack Wext->Wa1, repack Wreg->Wa2. Roles by blockIdx.
// ---------------------------------------------------------------------------
__global__ __launch_bounds__(256) void prep(
    const float* __restrict__ x, const float* __restrict__ Wext,
    const float* __restrict__ Wreg, _Float16* __restrict__ xh,
    _Float16* __restrict__ Wa1, _Float16* __restrict__ Wa2,
    _Float16* __restrict__ fpad)
{
    const int bid = blockIdx.x;
    const int t   = threadIdx.x;
    if (bid < 16384) {
        // xh interior: task = (img, c8, h); 2 tasks/block, 128 px each
        const int task = bid * 2 + (t >> 7);
        const int img  = task >> 12;
        const int rem  = task & 4095;
        const int c8   = rem >> 7;
        const int h    = rem & 127;
        const int w    = t & 127;
        const float* xp = x + ((size_t)(img * 256 + c8 * 8)) * HW_ + h * W_ + w;
        half8 hv;
#pragma unroll
        for (int j = 0; j < 8; ++j) hv[j] = (_Float16)xp[j * HW_];
        *(half8*)(xh + ((((size_t)img * 32 + c8) * XHP_ + (h + 1)) * XHP_ + (w + 1)) * 8) = hv;
    } else if (bid < 16900) {
        // xh border zero: 516 px per (img,c8), 16B each; 516*256 = 132096 exact
        const int e  = (bid - 16384) * 256 + t;
        const int ic = e / 516;
        const int pe = e % 516;
        const int img = ic >> 5, c8 = ic & 31;
        int hp, wp;
        if (pe < 130)      { hp = 0;              wp = pe; }
        else if (pe < 260) { hp = 129;            wp = pe - 130; }
        else if (pe < 388) { hp = 1 + (pe - 260); wp = 0; }
        else               { hp = 1 + (pe - 388); wp = 129; }
        half8 z = {};
        *(half8*)(xh + ((((size_t)img * 32 + c8) * XHP_ + hp) * XHP_ + wp) * 8) = z;
    } else if (bid < 16965) {
        // fpad border zero: 1040 px/img * 2 halves * 8 img = 16640 units of 16B
        const int e = (bid - 16900) * 256 + t;
        if (e < 16640) {
            const int img = e / 2080;
            const int r   = e % 2080;
            const int pxi = r >> 1, hf = r & 1;
            int hp, wp;
            if (pxi < 264)      { hp = pxi / 132;                wp = pxi % 132; }
            else if (pxi < 528) { int pz = pxi - 264; hp = 130 + pz / 132; wp = pz % 132; }
            else { int q2 = pxi - 528; hp = 2 + (q2 >> 2); int s2 = q2 & 3;
                   wp = (s2 < 2) ? s2 : 128 + (s2 - 2); }
            half8 z = {};
            *(half8*)(fpad + (((size_t)img * HFP_ + hp) * HFP_ + wp) * 16 + hf * 8) = z;
        }
    } else if (bid < 17109) {
        // repack_w1: 144*256 = 36864 exact
        const int i = (bid - 16965) * 256 + t;
        const int j = i & 7, lane = (i >> 3) & 63, blk = (i >> 9) & 7, tap = i >> 12;
        const int cc  = lane & 15;
        const int cin = blk * 32 + (lane >> 4) * 8 + j;
        Wa1[i] = (_Float16)Wext[cc * (CIN_ * 9) + cin * 9 + tap];
    } else {
        // repack_w2: 104*256 = 26624 exact
        const int u = (bid - 17109) * 256 + t;
        const int j = u & 7, lane = (u >> 3) & 63;
        const int su = u >> 9, s = su % 13, g = su / 13;
        const int q = lane >> 4;
        int kk = 2 * s + (q >> 1);
        const int c = (q & 1) * 8 + j;
        const int o = g * 16 + (lane & 15);
        float v = (kk < 25) ? Wreg[o * (CC_ * 25) + c * 25 + kk] : 0.0f;
        Wa2[u] = (_Float16)v;
    }
}

// ---------------------------------------------------------------------------
// Fused Stage 1 v2: staging via global_load_lds from padded f16 xh.
// (round-5/6/7 bytes, verbatim)
// ---------------------------------------------------------------------------
__global__ __launch_bounds__(256, 4) void conv_fused2(
    const _Float16* __restrict__ xh, const _Float16* __restrict__ Wa1,
    const float* __restrict__ bext, _Float16* __restrict__ fpad)
{
    __shared__ _Float16 xs[2 * 6528];        // 26,112 B double-buffered staging
    __shared__ _Float16 lt[4][32][16];       // 4,096 B epilogue transpose

    const int lane = threadIdx.x;
    const int wv   = threadIdx.y;
    const int n    = lane & 15;
    const int q    = lane >> 4;

    // XCD swizzle: f bijective over 0..1023; b = f&7 pins image -> XCD
    const int f  = blockIdx.x + 4 * blockIdx.y + 128 * blockIdx.z;
    const int b  = f & 7;
    const int wt = (f >> 3) & 3;
    const int ht = f >> 5;
    const int h0 = ht * 4;
    const int w0 = wt * 32;

    // staging descriptors: unit u = wv*204 + k*64 + lane over [c8][row][col]
    const _Float16* xhb = xh + (size_t)b * XH_IMG;
    const _Float16* g[4];
#pragma unroll
    for (int k = 0; k < 4; ++k) {
        int u = wv * 204 + k * 64 + lane;
        if (k == 3 && lane >= 12) u = wv * 204;     // inactive lane, safe addr
        const int c8  = u / 204;
        const int rem = u % 204;
        const int row = rem / 34;
        const int col = rem % 34;
        g[k] = xhb + (((size_t)c8 * XHP_ + (h0 + row)) * XHP_ + (w0 + col)) * 8;
    }

    // prologue: stage chunk 0 -> buf0
#pragma unroll
    for (int k = 0; k < 4; ++k) {
        if (k < 3 || lane < 12) gload16(g[k], xs + (wv * 204 + k * 64) * 8);
        g[k] += XH_CHUNK;
    }
    asm volatile("s_waitcnt vmcnt(0)" ::: "memory");

    float4v acc[2] = {};
    for (int chunk = 0; chunk < 8; ++chunk) {
        __syncthreads();                     // xs[cur] staged by all waves
        const int cur = chunk & 1;

        if (chunk < 7) {
            _Float16* xd = xs + (cur ^ 1) * 6528;
#pragma unroll
            for (int k = 0; k < 4; ++k) {
                if (k < 3 || lane < 12) gload16(g[k], xd + (wv * 204 + k * 64) * 8);
                g[k] += XH_CHUNK;
            }
        }

        const _Float16* wchunk = Wa1 + (size_t)chunk * 512 + lane * 8;
        const _Float16* xsb    = xs + cur * 6528 + ((q * 6 + wv) * 34 + n) * 8;
#pragma unroll
        for (int r = 0; r < 3; ++r) {
#pragma unroll
            for (int s = 0; s < 3; ++s) {
                const half8 af = *(const half8*)(wchunk + (r * 3 + s) * 4096);
#pragma unroll
                for (int st = 0; st < 2; ++st) {
                    const half8 bf = *(const half8*)(xsb + (r * 34 + s + st * 16) * 8);
                    acc[st] = __builtin_amdgcn_mfma_f32_16x16x32_f16(af, bf, acc[st], 0, 0, 0);
                }
            }
        }
        asm volatile("s_waitcnt vmcnt(0)" ::: "memory");  // my DMA landed before barrier
    }

    // ---- epilogue: bias + f32->f16, per-wave LDS transpose, write fpad ----
    float bias[4];
#pragma unroll
    for (int rr = 0; rr < 4; ++rr) bias[rr] = bext[q * 4 + rr];

#pragma unroll
    for (int st = 0; st < 2; ++st) {
#pragma unroll
        for (int rr = 0; rr < 4; ++rr) {
            lt[wv][st * 16 + n][q * 4 + rr] = (_Float16)(acc[st][rr] + bias[rr]);
        }
    }
    __syncthreads();

    const half8 o = *(const half8*)&lt[wv][lane >> 1][(lane & 1) * 8];
    _Float16* dst = fpad + (((size_t)b * HFP_ + (h0 + wv + 2)) * HFP_ + (w0 + (lane >> 1) + 2)) * 16
                    + (lane & 1) * 8;
    *(half8*)dst = o;
}

// ---------------------------------------------------------------------------
// FALLBACK kernels (used when ws_size is too small for xh).
// ---------------------------------------------------------------------------
__global__ void repack_w1(const float* __restrict__ Wext, _Float16* __restrict__ Wa1) {
    int i = blockIdx.x * 256 + threadIdx.x;
    if (i >= 9 * 8 * 64 * 8) return;
    int j    = i & 7;
    int lane = (i >> 3) & 63;
    int blk  = (i >> 9) & 7;
    int tap  = i >> 12;
    int cc   = lane & 15;
    int cin  = blk * 32 + (lane >> 4) * 8 + j;
    Wa1[i] = (_Float16)Wext[cc * (CIN_ * 9) + cin * 9 + tap];
}

__global__ void repack_w2(const float* __restrict__ Wreg, _Float16* __restrict__ Wa2) {
    int u = blockIdx.x * 256 + threadIdx.x;
    if (u >= 4 * 13 * 64 * 8) return;
    int j    = u & 7;
    int lane = (u >> 3) & 63;
    int su   = u >> 9;
    int s    = su % 13;
    int g    = su / 13;
    int q    = lane >> 4;
    int kk   = 2 * s + (q >> 1);
    int c    = (q & 1) * 8 + j;
    int o    = g * 16 + (lane & 15);
    float v  = (kk < 25) ? Wreg[o * (CC_ * 25) + c * 25 + kk] : 0.0f;
    Wa2[u] = (_Float16)v;
}

__global__ __launch_bounds__(256, 4) void conv_fused(
    const float* __restrict__ x, const _Float16* __restrict__ Wa1,
    const float* __restrict__ bext, _Float16* __restrict__ fpad)
{
    __shared__ _Float16 xs[2 * XS_BUF];
    __shared__ _Float16 lt[4][32][16];

    const int lane = threadIdx.x;
    const int wv   = threadIdx.y;
    const int tid  = wv * 64 + lane;
    const int n    = lane & 15;
    const int q    = lane >> 4;

    const int f  = blockIdx.x + 4 * blockIdx.y + 128 * blockIdx.z;
    const int b  = f & 7;
    const int wt = (f >> 3) & 3;
    const int ht = f >> 5;
    const int h0 = ht * 4;
    const int w0 = wt * 32;

    int  goff[4];
    int  loff[4];
    bool vld[4];
    bool act[4];
#pragma unroll
    for (int p = 0; p < 4; ++p) {
        int u = p * 256 + tid;
        act[p] = (u < 816);
        if (!act[p]) u = 0;
        const int col  = u % 34;
        const int pair = u / 34;
        const int row  = pair % 6;
        const int c8   = pair / 6;
        const int hh = h0 - 1 + row;
        const int ww = w0 - 1 + col;
        vld[p] = (hh >= 0) && (hh < H_) && (ww >= 0) && (ww < W_);
        const int hc = hh < 0 ? 0 : (hh > H_ - 1 ? H_ - 1 : hh);
        const int wc = ww < 0 ? 0 : (ww > W_ - 1 ? W_ - 1 : ww);
        goff[p] = (c8 * 8) * HW_ + hc * W_ + wc;
        loff[p] = c8 * XS_STRIDE + (row * 34 + col) * 8;
    }

    const float* xb = x + (size_t)b * (CIN_ * HW_);
    float4v acc[2] = {};

#pragma unroll
    for (int p = 0; p < 4; ++p) {
        if (act[p]) {
            half8 hv;
#pragma unroll
            for (int j = 0; j < 8; ++j) {
                const float v = xb[goff[p] + j * HW_];
                hv[j] = (_Float16)(vld[p] ? v : 0.0f);
            }
            *(half8*)(xs + loff[p]) = hv;
        }
    }

    float pf[4][8];
    for (int chunk = 0; chunk < 8; ++chunk) {
        __syncthreads();
        const int cur = chunk & 1;

        if (chunk < 7) {
            const float* xc = xb + (size_t)(chunk + 1) * (32 * HW_);
#pragma unroll
            for (int p = 0; p < 4; ++p) {
                if (act[p]) {
#pragma unroll
                    for (int j = 0; j < 8; ++j)
                        pf[p][j] = xc[goff[p] + j * HW_];
                }
            }
        }

        const _Float16* wchunk = Wa1 + (size_t)chunk * 512 + lane * 8;
        const _Float16* xsb    = xs + cur * XS_BUF + q * XS_STRIDE + (wv * 34 + n) * 8;
#pragma unroll
        for (int r = 0; r < 3; ++r) {
#pragma unroll
            for (int s = 0; s < 3; ++s) {
                const half8 af = *(const half8*)(wchunk + (r * 3 + s) * 4096);
#pragma unroll
                for (int st = 0; st < 2; ++st) {
                    const half8 bf = *(const half8*)(xsb + (r * 34 + s + st * 16) * 8);
                    acc[st] = __builtin_amdgcn_mfma_f32_16x16x32_f16(af, bf, acc[st], 0, 0, 0);
                }
            }
        }

        if (chunk < 7) {
            _Float16* xd = xs + (cur ^ 1) * XS_BUF;
#pragma unroll
            for (int p = 0; p < 4; ++p) {
                if (act[p]) {
                    half8 hv;
#pragma unroll
                    for (int j = 0; j < 8; ++j)
                        hv[j] = (_Float16)(vld[p] ? pf[p][j] : 0.0f);
                    *(half8*)(xd + loff[p]) = hv;
                }
            }
        }
    }

    float bias[4];
#pragma unroll
    for (int rr = 0; rr < 4; ++rr) bias[rr] = bext[q * 4 + rr];

#pragma unroll
    for (int st = 0; st < 2; ++st) {
#pragma unroll
        for (int rr = 0; rr < 4; ++rr) {
            lt[wv][st * 16 + n][q * 4 + rr] = (_Float16)(acc[st][rr] + bias[rr]);
        }
    }
    __syncthreads();

    const half8 o = *(const half8*)&lt[wv][lane >> 1][(lane & 1) * 8];
    _Float16* dst = fpad + (((size_t)b * HFP_ + (h0 + wv + 2)) * HFP_ + (w0 + (lane >> 1) + 2)) * 16
                    + (lane & 1) * 8;
    *(half8*)dst = o;
}

// ---------------------------------------------------------------------------
// Stage 2: corr + regressor via MFMA.
// v4 (from round-7 counters: FETCH=105 MB/rep = total request volume -> 0%
// L2 read hit; WRITE=4.1x unique bytes -> partial-line write-allocate churn).
// Fixes:
//  (a) LDS-transpose epilogue: block's 64x64 f32 out-tile staged in LDS,
//      then each 16-lane group writes one FULL 256 B o-row (float4/lane) --
//      no partial lines, no RFO.
//  (b) nontemporal stores: out never allocates in L2 -> fpad (557 KB/XCD)
//      and Wa2 (53 KB) stay L2-resident -> fpad reads hit.
// ---------------------------------------------------------------------------
__global__ __launch_bounds__(256, 4) void corr_mfma(
    const _Float16* __restrict__ fpad, const _Float16* __restrict__ Wa2,
    float* __restrict__ out)
{
    __shared__ float ot[64 * 65];            // 16,640 B out-tile transpose (stride 65)

    const int lane = threadIdx.x;
    const int wv   = threadIdx.y;
    const int n    = lane & 15;
    const int q    = lane >> 4;

    const int f  = blockIdx.x + 2 * blockIdx.y + 256 * blockIdx.z;
    const int b  = f & 7;
    const int xt = (f >> 3) & 1;
    const int h  = f >> 4;
    const int w0 = xt * 64 + wv * 16;

    const _Float16* fb = fpad + ((size_t)b * HFP_ + h) * (HFP_ * 16);
    const int coff = (q & 1) * 8;

    // issue all 14 loads (ctr + 13 shifted fragments) as one batch
    const half8 ctr = *(const half8*)(fb + (size_t)(2 * HFP_ + (w0 + n + 2)) * 16 + coff);
    half8 sh[13];
#pragma unroll
    for (int s = 0; s < 13; ++s) {
        int kk = 2 * s + (q >> 1);
        if (kk > 24) kk = 24;                 // s=12,q>=2: weights are zero
        const int ki = kk / 5, kj = kk % 5;
        sh[s] = *(const half8*)(fb + (size_t)(ki * HFP_ + (w0 + n + kj)) * 16 + coff);
    }
    __builtin_amdgcn_sched_barrier(0);        // loads may not sink below here

    float4v acc[4] = {};
    const _Float16* wp = Wa2 + (size_t)lane * 8;
#pragma unroll
    for (int s = 0; s < 13; ++s) {
        const half8 c = ctr * sh[s];          // single temp, consumed immediately
#pragma unroll
        for (int g = 0; g < 4; ++g) {
            const half8 wf = *(const half8*)(wp + (size_t)(g * 13 + s) * 512);
            acc[g] = __builtin_amdgcn_mfma_f32_16x16x32_f16(wf, c, acc[g], 0, 0, 0);
        }
    }

    // stage out-tile in LDS: ot[o][w_local], o = g*16+q*4+rr, w_local = wv*16+n
#pragma unroll
    for (int g = 0; g < 4; ++g) {
#pragma unroll
        for (int rr = 0; rr < 4; ++rr) {
            ot[(g * 16 + q * 4 + rr) * 65 + wv * 16 + n] = acc[g][rr];
        }
    }
    __syncthreads();

    // coalesced nontemporal writeback: each 16-lane group writes one full
    // 256 B o-row (float4 per lane); 4 rows per wave per iteration.
#pragma unroll
    for (int i = 0; i < 4; ++i) {
        const int o  = wv * 16 + i * 4 + q;
        const int wl = n * 4;
        float4v v;
        v[0] = ot[o * 65 + wl + 0];
        v[1] = ot[o * 65 + wl + 1];
        v[2] = ot[o * 65 + wl + 2];
        v[3] = ot[o * 65 + wl + 3];
        float* dst = out + (((size_t)(b * COUT_ + o) * H_ + h) * W_ + xt * 64 + wl);
        __builtin_nontemporal_store(v, (float4v*)dst);
    }
}

// ---------------------------------------------------------------------------
extern "C" void kernel_launch(void* const* d_in, const int* in_sizes, int n_in,
                              void* d_out, int out_size, void* d_ws, size_t ws_size,
                              hipStream_t stream) {
    const float* x    = (const float*)d_in[0];  // (8,256,128,128)
    const float* Wext = (const float*)d_in[1];  // (16,256,3,3)
    const float* bext = (const float*)d_in[2];  // (16,)
    const float* Wreg = (const float*)d_in[3];  // (64,16,5,5)
    float* out = (float*)d_out;                 // (8,64,128,128)

    char* ws = (char*)d_ws;
    _Float16* fpad = (_Float16*)ws;                       // 4,460,544 B
    _Float16* Wa1  = (_Float16*)(ws + 4460544);           // 73,728 B
    _Float16* Wa2  = (_Float16*)(ws + 4460544 + 73728);   // 53,248 B
    const size_t XH_OFF = 4460544 + 73728 + 53248;        // 4,587,520
    const size_t XH_B   = (size_t)8 * 32 * XHP_ * XHP_ * 8 * 2;  // 69,222,400

    if (ws_size >= XH_OFF + XH_B) {
        _Float16* xh = (_Float16*)(ws + XH_OFF);
        prep<<<dim3(17213), dim3(256), 0, stream>>>(x, Wext, Wreg, xh, Wa1, Wa2, fpad);
        conv_fused2<<<dim3(4, 32, 8), dim3(64, 4), 0, stream>>>(xh, Wa1, bext, fpad);
        corr_mfma<<<dim3(2, 128, 8), dim3(64, 4), 0, stream>>>(fpad, Wa2, out);
    } else {
        repack_w1<<<dim3(144), dim3(256), 0, stream>>>(Wext, Wa1);
        repack_w2<<<dim3(104), dim3(256), 0, stream>>>(Wreg, Wa2);
        hipMemsetAsync(fpad, 0, (size_t)B_ * CC_ * HFP_ * HFP_ * sizeof(_Float16), stream);
        conv_fused<<<dim3(4, 32, 8), dim3(64, 4), 0, stream>>>(x, Wa1, bext, fpad);
        corr_mfma<<<dim3(2, 128, 8), dim3(64, 4), 0, stream>>>(fpad, Wa2, out);
    }
}

// Round 10
// 244.325 us; speedup vs baseline: 1.5365x; 1.0125x over previous
//
#include <hip/hip_runtime.h>

#define B_    8
#define CIN_  256
#define H_    128
#define W_    128
#define CC_   16
#define COUT_ 64
#define HFP_  132            // fpad padded dim (pad 2)
#define HW_   (H_ * W_)
#define XHP_  130            // xh padded dim (pad 1)
#define XH_IMG   ((size_t)32 * XHP_ * XHP_ * 8)   // 4,326,400 f16 per image
#define XH_CHUNK (4 * XHP_ * XHP_ * 8)            // 540,800 f16 per 32-cin chunk

// old-path LDS staging constants (fallback kernel)
#define XS_STRIDE 1634
#define XS_BUF    (4 * XS_STRIDE)

typedef _Float16 half8 __attribute__((ext_vector_type(8)));
typedef float float4v __attribute__((ext_vector_type(4)));

__device__ __forceinline__ void gload16(const _Float16* g, _Float16* l) {
    __builtin_amdgcn_global_load_lds(
        (const __attribute__((address_space(1))) void*)g,
        (__attribute__((address_space(3))) void*)l, 16, 0, 0);
}

// ---------------------------------------------------------------------------
// PREP (one dispatch): x->xh f16 transpose+pad, xh border zero,
// fpad border zero, repack Wext->Wa1, repack Wreg->Wa2. Roles by blockIdx.
// ---------------------------------------------------------------------------
__global__ __launch_bounds__(256) void prep(
    const float* __restrict__ x, const float* __restrict__ Wext,
    const float* __restrict__ Wreg, _Float16* __restrict__ xh,
    _Float16* __restrict__ Wa1, _Float16* __restrict__ Wa2,
    _Float16* __restrict__ fpad)
{
    const int bid = blockIdx.x;
    const int t   = threadIdx.x;
    if (bid < 16384) {
        // xh interior: task = (img, c8, h); 2 tasks/block, 128 px each
        const int task = bid * 2 + (t >> 7);
        const int img  = task >> 12;
        const int rem  = task & 4095;
        const int c8   = rem >> 7;
        const int h    = rem & 127;
        const int w    = t & 127;
        const float* xp = x + ((size_t)(img * 256 + c8 * 8)) * HW_ + h * W_ + w;
        half8 hv;
#pragma unroll
        for (int j = 0; j < 8; ++j) hv[j] = (_Float16)xp[j * HW_];
        *(half8*)(xh + ((((size_t)img * 32 + c8) * XHP_ + (h + 1)) * XHP_ + (w + 1)) * 8) = hv;
    } else if (bid < 16900) {
        // xh border zero: 516 px per (img,c8), 16B each; 516*256 = 132096 exact
        const int e  = (bid - 16384) * 256 + t;
        const int ic = e / 516;
        const int pe = e % 516;
        const int img = ic >> 5, c8 = ic & 31;
        int hp, wp;
        if (pe < 130)      { hp = 0;              wp = pe; }
        else if (pe < 260) { hp = 129;            wp = pe - 130; }
        else if (pe < 388) { hp = 1 + (pe - 260); wp = 0; }
        else               { hp = 1 + (pe - 388); wp = 129; }
        half8 z = {};
        *(half8*)(xh + ((((size_t)img * 32 + c8) * XHP_ + hp) * XHP_ + wp) * 8) = z;
    } else if (bid < 16965) {
        // fpad border zero: 1040 px/img * 2 halves * 8 img = 16640 units of 16B
        const int e = (bid - 16900) * 256 + t;
        if (e < 16640) {
            const int img = e / 2080;
            const int r   = e % 2080;
            const int pxi = r >> 1, hf = r & 1;
            int hp, wp;
            if (pxi < 264)      { hp = pxi / 132;                wp = pxi % 132; }
            else if (pxi < 528) { int pz = pxi - 264; hp = 130 + pz / 132; wp = pz % 132; }
            else { int q2 = pxi - 528; hp = 2 + (q2 >> 2); int s2 = q2 & 3;
                   wp = (s2 < 2) ? s2 : 128 + (s2 - 2); }
            half8 z = {};
            *(half8*)(fpad + (((size_t)img * HFP_ + hp) * HFP_ + wp) * 16 + hf * 8) = z;
        }
    } else if (bid < 17109) {
        // repack_w1: 144*256 = 36864 exact
        const int i = (bid - 16965) * 256 + t;
        const int j = i & 7, lane = (i >> 3) & 63, blk = (i >> 9) & 7, tap = i >> 12;
        const int cc  = lane & 15;
        const int cin = blk * 32 + (lane >> 4) * 8 + j;
        Wa1[i] = (_Float16)Wext[cc * (CIN_ * 9) + cin * 9 + tap];
    } else {
        // repack_w2: 104*256 = 26624 exact
        const int u = (bid - 17109) * 256 + t;
        const int j = u & 7, lane = (u >> 3) & 63;
        const int su = u >> 9, s = su % 13, g = su / 13;
        const int q = lane >> 4;
        int kk = 2 * s + (q >> 1);
        const int c = (q & 1) * 8 + j;
        const int o = g * 16 + (lane & 15);
        float v = (kk < 25) ? Wreg[o * (CC_ * 25) + c * 25 + kk] : 0.0f;
        Wa2[u] = (_Float16)v;
    }
}

// ---------------------------------------------------------------------------
// Fused Stage 1 v2: staging via global_load_lds from padded f16 xh.
// (round-5..8 bytes, verbatim)
// ---------------------------------------------------------------------------
__global__ __launch_bounds__(256, 4) void conv_fused2(
    const _Float16* __restrict__ xh, const _Float16* __restrict__ Wa1,
    const float* __restrict__ bext, _Float16* __restrict__ fpad)
{
    __shared__ _Float16 xs[2 * 6528];        // 26,112 B double-buffered staging
    __shared__ _Float16 lt[4][32][16];       // 4,096 B epilogue transpose

    const int lane = threadIdx.x;
    const int wv   = threadIdx.y;
    const int n    = lane & 15;
    const int q    = lane >> 4;

    // XCD swizzle: f bijective over 0..1023; b = f&7 pins image -> XCD
    const int f  = blockIdx.x + 4 * blockIdx.y + 128 * blockIdx.z;
    const int b  = f & 7;
    const int wt = (f >> 3) & 3;
    const int ht = f >> 5;
    const int h0 = ht * 4;
    const int w0 = wt * 32;

    // staging descriptors: unit u = wv*204 + k*64 + lane over [c8][row][col]
    const _Float16* xhb = xh + (size_t)b * XH_IMG;
    const _Float16* g[4];
#pragma unroll
    for (int k = 0; k < 4; ++k) {
        int u = wv * 204 + k * 64 + lane;
        if (k == 3 && lane >= 12) u = wv * 204;     // inactive lane, safe addr
        const int c8  = u / 204;
        const int rem = u % 204;
        const int row = rem / 34;
        const int col = rem % 34;
        g[k] = xhb + (((size_t)c8 * XHP_ + (h0 + row)) * XHP_ + (w0 + col)) * 8;
    }

    // prologue: stage chunk 0 -> buf0
#pragma unroll
    for (int k = 0; k < 4; ++k) {
        if (k < 3 || lane < 12) gload16(g[k], xs + (wv * 204 + k * 64) * 8);
        g[k] += XH_CHUNK;
    }
    asm volatile("s_waitcnt vmcnt(0)" ::: "memory");

    float4v acc[2] = {};
    for (int chunk = 0; chunk < 8; ++chunk) {
        __syncthreads();                     // xs[cur] staged by all waves
        const int cur = chunk & 1;

        if (chunk < 7) {
            _Float16* xd = xs + (cur ^ 1) * 6528;
#pragma unroll
            for (int k = 0; k < 4; ++k) {
                if (k < 3 || lane < 12) gload16(g[k], xd + (wv * 204 + k * 64) * 8);
                g[k] += XH_CHUNK;
            }
        }

        const _Float16* wchunk = Wa1 + (size_t)chunk * 512 + lane * 8;
        const _Float16* xsb    = xs + cur * 6528 + ((q * 6 + wv) * 34 + n) * 8;
#pragma unroll
        for (int r = 0; r < 3; ++r) {
#pragma unroll
            for (int s = 0; s < 3; ++s) {
                const half8 af = *(const half8*)(wchunk + (r * 3 + s) * 4096);
#pragma unroll
                for (int st = 0; st < 2; ++st) {
                    const half8 bf = *(const half8*)(xsb + (r * 34 + s + st * 16) * 8);
                    acc[st] = __builtin_amdgcn_mfma_f32_16x16x32_f16(af, bf, acc[st], 0, 0, 0);
                }
            }
        }
        asm volatile("s_waitcnt vmcnt(0)" ::: "memory");  // my DMA landed before barrier
    }

    // ---- epilogue: bias + f32->f16, per-wave LDS transpose, write fpad ----
    float bias[4];
#pragma unroll
    for (int rr = 0; rr < 4; ++rr) bias[rr] = bext[q * 4 + rr];

#pragma unroll
    for (int st = 0; st < 2; ++st) {
#pragma unroll
        for (int rr = 0; rr < 4; ++rr) {
            lt[wv][st * 16 + n][q * 4 + rr] = (_Float16)(acc[st][rr] + bias[rr]);
        }
    }
    __syncthreads();

    const half8 o = *(const half8*)&lt[wv][lane >> 1][(lane & 1) * 8];
    _Float16* dst = fpad + (((size_t)b * HFP_ + (h0 + wv + 2)) * HFP_ + (w0 + (lane >> 1) + 2)) * 16
                    + (lane & 1) * 8;
    *(half8*)dst = o;
}

// ---------------------------------------------------------------------------
// FALLBACK kernels (used when ws_size is too small for xh).
// ---------------------------------------------------------------------------
__global__ void repack_w1(const float* __restrict__ Wext, _Float16* __restrict__ Wa1) {
    int i = blockIdx.x * 256 + threadIdx.x;
    if (i >= 9 * 8 * 64 * 8) return;
    int j    = i & 7;
    int lane = (i >> 3) & 63;
    int blk  = (i >> 9) & 7;
    int tap  = i >> 12;
    int cc   = lane & 15;
    int cin  = blk * 32 + (lane >> 4) * 8 + j;
    Wa1[i] = (_Float16)Wext[cc * (CIN_ * 9) + cin * 9 + tap];
}

__global__ void repack_w2(const float* __restrict__ Wreg, _Float16* __restrict__ Wa2) {
    int u = blockIdx.x * 256 + threadIdx.x;
    if (u >= 4 * 13 * 64 * 8) return;
    int j    = u & 7;
    int lane = (u >> 3) & 63;
    int su   = u >> 9;
    int s    = su % 13;
    int g    = su / 13;
    int q    = lane >> 4;
    int kk   = 2 * s + (q >> 1);
    int c    = (q & 1) * 8 + j;
    int o    = g * 16 + (lane & 15);
    float v  = (kk < 25) ? Wreg[o * (CC_ * 25) + c * 25 + kk] : 0.0f;
    Wa2[u] = (_Float16)v;
}

__global__ __launch_bounds__(256, 4) void conv_fused(
    const float* __restrict__ x, const _Float16* __restrict__ Wa1,
    const float* __restrict__ bext, _Float16* __restrict__ fpad)
{
    __shared__ _Float16 xs[2 * XS_BUF];
    __shared__ _Float16 lt[4][32][16];

    const int lane = threadIdx.x;
    const int wv   = threadIdx.y;
    const int tid  = wv * 64 + lane;
    const int n    = lane & 15;
    const int q    = lane >> 4;

    const int f  = blockIdx.x + 4 * blockIdx.y + 128 * blockIdx.z;
    const int b  = f & 7;
    const int wt = (f >> 3) & 3;
    const int ht = f >> 5;
    const int h0 = ht * 4;
    const int w0 = wt * 32;

    int  goff[4];
    int  loff[4];
    bool vld[4];
    bool act[4];
#pragma unroll
    for (int p = 0; p < 4; ++p) {
        int u = p * 256 + tid;
        act[p] = (u < 816);
        if (!act[p]) u = 0;
        const int col  = u % 34;
        const int pair = u / 34;
        const int row  = pair % 6;
        const int c8   = pair / 6;
        const int hh = h0 - 1 + row;
        const int ww = w0 - 1 + col;
        vld[p] = (hh >= 0) && (hh < H_) && (ww >= 0) && (ww < W_);
        const int hc = hh < 0 ? 0 : (hh > H_ - 1 ? H_ - 1 : hh);
        const int wc = ww < 0 ? 0 : (ww > W_ - 1 ? W_ - 1 : ww);
        goff[p] = (c8 * 8) * HW_ + hc * W_ + wc;
        loff[p] = c8 * XS_STRIDE + (row * 34 + col) * 8;
    }

    const float* xb = x + (size_t)b * (CIN_ * HW_);
    float4v acc[2] = {};

#pragma unroll
    for (int p = 0; p < 4; ++p) {
        if (act[p]) {
            half8 hv;
#pragma unroll
            for (int j = 0; j < 8; ++j) {
                const float v = xb[goff[p] + j * HW_];
                hv[j] = (_Float16)(vld[p] ? v : 0.0f);
            }
            *(half8*)(xs + loff[p]) = hv;
        }
    }

    float pf[4][8];
    for (int chunk = 0; chunk < 8; ++chunk) {
        __syncthreads();
        const int cur = chunk & 1;

        if (chunk < 7) {
            const float* xc = xb + (size_t)(chunk + 1) * (32 * HW_);
#pragma unroll
            for (int p = 0; p < 4; ++p) {
                if (act[p]) {
#pragma unroll
                    for (int j = 0; j < 8; ++j)
                        pf[p][j] = xc[goff[p] + j * HW_];
                }
            }
        }

        const _Float16* wchunk = Wa1 + (size_t)chunk * 512 + lane * 8;
        const _Float16* xsb    = xs + cur * XS_BUF + q * XS_STRIDE + (wv * 34 + n) * 8;
#pragma unroll
        for (int r = 0; r < 3; ++r) {
#pragma unroll
            for (int s = 0; s < 3; ++s) {
                const half8 af = *(const half8*)(wchunk + (r * 3 + s) * 4096);
#pragma unroll
                for (int st = 0; st < 2; ++st) {
                    const half8 bf = *(const half8*)(xsb + (r * 34 + s + st * 16) * 8);
                    acc[st] = __builtin_amdgcn_mfma_f32_16x16x32_f16(af, bf, acc[st], 0, 0, 0);
                }
            }
        }

        if (chunk < 7) {
            _Float16* xd = xs + (cur ^ 1) * XS_BUF;
#pragma unroll
            for (int p = 0; p < 4; ++p) {
                if (act[p]) {
                    half8 hv;
#pragma unroll
                    for (int j = 0; j < 8; ++j)
                        hv[j] = (_Float16)(vld[p] ? pf[p][j] : 0.0f);
                    *(half8*)(xd + loff[p]) = hv;
                }
            }
        }
    }

    float bias[4];
#pragma unroll
    for (int rr = 0; rr < 4; ++rr) bias[rr] = bext[q * 4 + rr];

#pragma unroll
    for (int st = 0; st < 2; ++st) {
#pragma unroll
        for (int rr = 0; rr < 4; ++rr) {
            lt[wv][st * 16 + n][q * 4 + rr] = (_Float16)(acc[st][rr] + bias[rr]);
        }
    }
    __syncthreads();

    const half8 o = *(const half8*)&lt[wv][lane >> 1][(lane & 1) * 8];
    _Float16* dst = fpad + (((size_t)b * HFP_ + (h0 + wv + 2)) * HFP_ + (w0 + (lane >> 1) + 2)) * 16
                    + (lane & 1) * 8;
    *(half8*)dst = o;
}

// ---------------------------------------------------------------------------
// Stage 2: corr + regressor via MFMA.
// v6: read path decoupled from L2 (round-7 diagnostic: FETCH = request
// volume -> 0% L2 hit; round-8 write-side fix falsified the thrash theory).
// Stage the block's fpad window (rows h..h+4, cols c0..c0+67, 16 cc =
// 10,880 B) into LDS via global_load_lds DMA: global requests drop
// 51.2 KB -> 10.9 KB per block, perfectly coalesced. Fragment reads become
// ds_read_b128 at 16 B lane stride (2 lanes/bank = free).
// LDS slot u = (cc_half*5 + row)*68 + col, 680 slots of 16 B.
// Epilogue (ot transpose + nontemporal full-line stores) unchanged.
// ---------------------------------------------------------------------------
__global__ __launch_bounds__(256, 4) void corr_mfma(
    const _Float16* __restrict__ fpad, const _Float16* __restrict__ Wa2,
    float* __restrict__ out)
{
    __shared__ _Float16 xs2[680 * 8];        // 10,880 B staged fpad window
    __shared__ float ot[64 * 65];            // 16,640 B out-tile transpose

    const int lane = threadIdx.x;
    const int wv   = threadIdx.y;
    const int tid  = wv * 64 + lane;
    const int n    = lane & 15;
    const int q    = lane >> 4;

    const int f  = blockIdx.x + 2 * blockIdx.y + 256 * blockIdx.z;
    const int b  = f & 7;
    const int xt = (f >> 3) & 1;
    const int h  = f >> 4;
    const int c0 = xt * 64;

    // ---- DMA-stage the fpad window ----
    const _Float16* fb2 = fpad + (((size_t)b * HFP_ + h) * HFP_ + c0) * 16;
#pragma unroll
    for (int k = 0; k < 3; ++k) {
        const int u0 = k * 256 + wv * 64;    // wave-uniform LDS batch base
        int u = u0 + lane;
        if (u > 679) u = 679;                // clamped lanes are predicated off
        const int half = u / 340;
        const int rem  = u % 340;
        const int row  = rem / 68;
        const int col  = rem % 68;
        if (k < 2 || tid < 168)
            gload16(fb2 + ((size_t)row * HFP_ + col) * 16 + half * 8,
                    xs2 + (size_t)u0 * 8);
    }
    asm volatile("s_waitcnt vmcnt(0)" ::: "memory");
    __syncthreads();

    // ---- compute from LDS ----
    const int half = q & 1;
    const int cb   = wv * 16 + n;            // local col base (0..63)
    const half8 ctr = *(const half8*)(xs2 + (size_t)((half * 5 + 2) * 68 + cb + 2) * 8);

    float4v acc[4] = {};
    const _Float16* wp = Wa2 + (size_t)lane * 8;
#pragma unroll
    for (int s = 0; s < 13; ++s) {
        int kk = 2 * s + (q >> 1);
        if (kk > 24) kk = 24;                 // s=12,q>=2: weights are zero
        const int ki = kk / 5, kj = kk % 5;
        const half8 sh = *(const half8*)(xs2 + (size_t)((half * 5 + ki) * 68 + cb + kj) * 8);
        const half8 c = ctr * sh;             // 4x v_pk_mul_f16
#pragma unroll
        for (int g = 0; g < 4; ++g) {
            const half8 wf = *(const half8*)(wp + (size_t)(g * 13 + s) * 512);
            acc[g] = __builtin_amdgcn_mfma_f32_16x16x32_f16(wf, c, acc[g], 0, 0, 0);
        }
    }

    // stage out-tile in LDS: ot[o][w_local], o = g*16+q*4+rr, w_local = wv*16+n
#pragma unroll
    for (int g = 0; g < 4; ++g) {
#pragma unroll
        for (int rr = 0; rr < 4; ++rr) {
            ot[(g * 16 + q * 4 + rr) * 65 + wv * 16 + n] = acc[g][rr];
        }
    }
    __syncthreads();

    // coalesced nontemporal writeback: each 16-lane group writes one full
    // 256 B o-row (float4 per lane); 4 rows per wave.
#pragma unroll
    for (int i = 0; i < 4; ++i) {
        const int o  = wv * 16 + i * 4 + q;
        const int wl = n * 4;
        float4v v;
        v[0] = ot[o * 65 + wl + 0];
        v[1] = ot[o * 65 + wl + 1];
        v[2] = ot[o * 65 + wl + 2];
        v[3] = ot[o * 65 + wl + 3];
        float* dst = out + (((size_t)(b * COUT_ + o) * H_ + h) * W_ + xt * 64 + wl);
        __builtin_nontemporal_store(v, (float4v*)dst);
    }
}

// ---------------------------------------------------------------------------
extern "C" void kernel_launch(void* const* d_in, const int* in_sizes, int n_in,
                              void* d_out, int out_size, void* d_ws, size_t ws_size,
                              hipStream_t stream) {
    const float* x    = (const float*)d_in[0];  // (8,256,128,128)
    const float* Wext = (const float*)d_in[1];  // (16,256,3,3)
    const float* bext = (const float*)d_in[2];  // (16,)
    const float* Wreg = (const float*)d_in[3];  // (64,16,5,5)
    float* out = (float*)d_out;                 // (8,64,128,128)

    char* ws = (char*)d_ws;
    _Float16* fpad = (_Float16*)ws;                       // 4,460,544 B
    _Float16* Wa1  = (_Float16*)(ws + 4460544);           // 73,728 B
    _Float16* Wa2  = (_Float16*)(ws + 4460544 + 73728);   // 53,248 B
    const size_t XH_OFF = 4460544 + 73728 + 53248;        // 4,587,520
    const size_t XH_B   = (size_t)8 * 32 * XHP_ * XHP_ * 8 * 2;  // 69,222,400

    if (ws_size >= XH_OFF + XH_B) {
        _Float16* xh = (_Float16*)(ws + XH_OFF);
        prep<<<dim3(17213), dim3(256), 0, stream>>>(x, Wext, Wreg, xh, Wa1, Wa2, fpad);
        conv_fused2<<<dim3(4, 32, 8), dim3(64, 4), 0, stream>>>(xh, Wa1, bext, fpad);
        corr_mfma<<<dim3(2, 128, 8), dim3(64, 4), 0, stream>>>(fpad, Wa2, out);
    } else {
        repack_w1<<<dim3(144), dim3(256), 0, stream>>>(Wext, Wa1);
        repack_w2<<<dim3(104), dim3(256), 0, stream>>>(Wreg, Wa2);
        hipMemsetAsync(fpad, 0, (size_t)B_ * CC_ * HFP_ * HFP_ * sizeof(_Float16), stream);
        conv_fused<<<dim3(4, 32, 8), dim3(64, 4), 0, stream>>>(x, Wa1, bext, fpad);
        corr_mfma<<<dim3(2, 128, 8), dim3(64, 4), 0, stream>>>(fpad, Wa2, out);
    }
}